// Round 9
// baseline (126.843 us; speedup 1.0000x reference)
//
#include <hip/hip_runtime.h>
#include <hip/hip_bf16.h>
#include <math.h>

#define Dm 128
#define Lc 4
#define Kc 7
#define Hh 8
#define Bb 64
#define Ss 400
#define SsP 448      // padded S for V^T rows (covers 64k-chunk tail reads)
#define TOK (Bb*Ss)   // 25600

typedef __attribute__((ext_vector_type(8))) short bf16x8;
typedef __attribute__((ext_vector_type(4))) float f32x4;

__device__ __forceinline__ float bf2f(unsigned int u) {
    union { unsigned int i; float f; } x; x.i = u << 16; return x.f;
}
__device__ __forceinline__ unsigned short f2bf(float f) {
    __hip_bfloat16 h = __float2bfloat16(f);
    return __builtin_bit_cast(unsigned short, h);
}
__device__ __forceinline__ unsigned int packbf(float a, float b) {
    return (unsigned int)f2bf(a) | ((unsigned int)f2bf(b) << 16);
}

// ---------- fused prep: pe (200) + repack_w (320) + merge_bias (4) + merge_conv (56) ----------

__global__ __launch_bounds__(256) void prep_all(const float* __restrict__ wq, const float* __restrict__ wk,
                                                const float* __restrict__ wv, const float* __restrict__ wp,
                                                const float* __restrict__ fc,
                                                const float* __restrict__ pw_w, const float* __restrict__ dw_w,
                                                const float* __restrict__ dw_b, const float* __restrict__ pw_b,
                                                float* __restrict__ pe, unsigned short* __restrict__ wf,
                                                float* __restrict__ mb, unsigned short* __restrict__ mwf) {
    __shared__ unsigned short hiS[64][136];
    __shared__ unsigned short loS[64][136];
    int blk = blockIdx.x;
    int tid = threadIdx.x;
    if (blk < 200) {                       // positional encoding, 2 rows/block
        int s = blk * 2 + (tid >> 7);
        int c = tid & 127;
        int j = (c < 64) ? c : (c - 64);
        float freq = expf(-(2.0f * j / 128.0f) * 9.210340371976184f);
        float a = (float)s * freq;
        pe[s * Dm + c] = (c < 64) ? sinf(a) : cosf(a);
        return;
    }
    if (blk < 520) {                       // repack 5 projection matrices to fragment-major
        int idx = (blk - 200) * 256 + tid;   // [0, 81920)
        int m = idx >> 14;
        int r = idx & 16383;
        int fragi = r >> 9, lr = (r >> 3) & 63, j = r & 7;
        int kb = fragi >> 3, nb = fragi & 7;
        int o = nb * 16 + (lr & 15);
        int d = kb * 32 + (lr >> 4) * 8 + j;
        const float* src = (m == 0) ? wq : (m == 1) ? wk : (m == 2) ? wv : (m == 3) ? wp : fc;
        wf[idx] = f2bf(src[o * Dm + d]);
        return;
    }
    if (blk < 524) {                       // merged conv bias
        int l = blk - 520;
        int f = tid;
        if (f < Dm) {
            const float* pwl = pw_w + ((size_t)l * Dm + f) * Dm;
            const float* db  = dw_b + l * Dm;
            float acc = pw_b[l * Dm + f];
            #pragma unroll 8
            for (int c4 = 0; c4 < 32; ++c4) {
                float4 p = *(const float4*)(pwl + c4 * 4);
                float4 d = *(const float4*)(db + c4 * 4);
                acc += p.x * d.x + p.y * d.y + p.z * d.z + p.w * d.w;
            }
            mb[l * Dm + f] = acc;
        }
        return;
    }
    // ---- merge conv weights (56 blocks), hi/lo split MFMA ----
    int mblk = blk - 524;
    int ih = mblk & 1;
    int k  = (mblk >> 1) % 7;
    int l  = mblk / 14;
    int lane = tid & 63, w = tid >> 6;

    const float* dwl = dw_w + (size_t)l * (Dm * Dm * Kc) + k;
    for (int it = 0; it < 32; ++it) {
        int idx = it * 256 + tid;          // 8192 = 128c x 64i
        int c = idx >> 6, il = idx & 63;
        int i = ih * 64 + il;
        float x = dwl[(size_t)(c * Dm + i) * Kc];
        unsigned short hi = f2bf(x);
        float lo = x - bf2f(hi);
        hiS[il][c] = hi;
        loS[il][c] = f2bf(lo);
    }
    __syncthreads();

    const float* pwl = pw_w + (size_t)l * Dm * Dm;
    int arow = lane & 15, ac = (lane >> 4) * 8;
    f32x4 acc[2][4];
    #pragma unroll
    for (int n = 0; n < 2; ++n)
        #pragma unroll
        for (int m = 0; m < 4; ++m) acc[n][m] = (f32x4){0.f, 0.f, 0.f, 0.f};

    #pragma unroll
    for (int kb = 0; kb < 4; ++kb) {
        int c0 = kb * 32 + ac;
        bf16x8 Bhi[2], Blo[2];
        #pragma unroll
        for (int n = 0; n < 2; ++n) {
            int f = (w * 2 + n) * 16 + arow;
            const float* rp = pwl + (size_t)f * Dm + c0;
            float4 a = *(const float4*)rp;
            float4 b = *(const float4*)(rp + 4);
            float v[8] = {a.x, a.y, a.z, a.w, b.x, b.y, b.z, b.w};
            unsigned short hh[8], ll[8];
            #pragma unroll
            for (int j = 0; j < 8; ++j) {
                hh[j] = f2bf(v[j]);
                ll[j] = f2bf(v[j] - bf2f(hh[j]));
            }
            uint4 uh = make_uint4((unsigned)hh[0] | ((unsigned)hh[1] << 16),
                                  (unsigned)hh[2] | ((unsigned)hh[3] << 16),
                                  (unsigned)hh[4] | ((unsigned)hh[5] << 16),
                                  (unsigned)hh[6] | ((unsigned)hh[7] << 16));
            uint4 ul = make_uint4((unsigned)ll[0] | ((unsigned)ll[1] << 16),
                                  (unsigned)ll[2] | ((unsigned)ll[3] << 16),
                                  (unsigned)ll[4] | ((unsigned)ll[5] << 16),
                                  (unsigned)ll[6] | ((unsigned)ll[7] << 16));
            Bhi[n] = __builtin_bit_cast(bf16x8, uh);
            Blo[n] = __builtin_bit_cast(bf16x8, ul);
        }
        #pragma unroll
        for (int m = 0; m < 4; ++m) {
            bf16x8 ahi = *(const bf16x8*)&hiS[m * 16 + arow][c0];
            bf16x8 alo = *(const bf16x8*)&loS[m * 16 + arow][c0];
            #pragma unroll
            for (int n = 0; n < 2; ++n) {
                acc[n][m] = __builtin_amdgcn_mfma_f32_16x16x32_bf16(ahi, Bhi[n], acc[n][m], 0, 0, 0);
                acc[n][m] = __builtin_amdgcn_mfma_f32_16x16x32_bf16(ahi, Blo[n], acc[n][m], 0, 0, 0);
                acc[n][m] = __builtin_amdgcn_mfma_f32_16x16x32_bf16(alo, Bhi[n], acc[n][m], 0, 0, 0);
            }
        }
    }
    #pragma unroll
    for (int n = 0; n < 2; ++n) {
        int nb = w * 2 + n;
        #pragma unroll
        for (int m = 0; m < 4; ++m) {
            int i0 = ih * 64 + m * 16 + (lane >> 4) * 4;
            int ib = i0 >> 5, i32 = i0 & 31;
            int lanep = ((i32 >> 3) << 4) | arow;
            int jb = i32 & 7;
            size_t frag = ((size_t)(l * 28 + (k * 4 + ib)) * 8 + nb);
            *(uint2*)(mwf + frag * 512 + lanep * 8 + jb) =
                make_uint2(packbf(acc[n][m][0], acc[n][m][1]),
                           packbf(acc[n][m][2], acc[n][m][3]));
        }
    }
}

// ---------- LN helpers: 16 consecutive lanes share one row ----------

__device__ __forceinline__ uint4 ln_core(float v[8],
                                         const float* __restrict__ g,
                                         const float* __restrict__ b, int c16) {
    float sum = 0.f, sq = 0.f;
    #pragma unroll
    for (int j = 0; j < 8; ++j) { sum += v[j]; sq += v[j] * v[j]; }
    #pragma unroll
    for (int off = 8; off; off >>= 1) {
        sum += __shfl_xor(sum, off);
        sq  += __shfl_xor(sq, off);
    }
    float mu = sum * (1.0f / 128.0f);
    float var = sq * (1.0f / 128.0f) - mu * mu;
    float rs = rsqrtf(var + 1e-5f);
    float4 g0 = *(const float4*)(g + c16 * 8);
    float4 g1 = *(const float4*)(g + c16 * 8 + 4);
    float4 b0 = *(const float4*)(b + c16 * 8);
    float4 b1 = *(const float4*)(b + c16 * 8 + 4);
    uint4 o;
    o.x = packbf((v[0] - mu) * rs * g0.x + b0.x, (v[1] - mu) * rs * g0.y + b0.y);
    o.y = packbf((v[2] - mu) * rs * g0.z + b0.z, (v[3] - mu) * rs * g0.w + b0.w);
    o.z = packbf((v[4] - mu) * rs * g1.x + b1.x, (v[5] - mu) * rs * g1.y + b1.y);
    o.w = packbf((v[6] - mu) * rs * g1.z + b1.z, (v[7] - mu) * rs * g1.w + b1.w);
    return o;
}

__device__ __forceinline__ uint4 ln_unpack_core(uint4 u,
                                                const float* __restrict__ g,
                                                const float* __restrict__ b, int c16) {
    float v[8] = { bf2f(u.x & 0xffffu), bf2f(u.x >> 16), bf2f(u.y & 0xffffu), bf2f(u.y >> 16),
                   bf2f(u.z & 0xffffu), bf2f(u.z >> 16), bf2f(u.w & 0xffffu), bf2f(u.w >> 16) };
    return ln_core(v, g, b, c16);
}

__device__ __forceinline__ uint4 ln_pack_bf(const unsigned short* __restrict__ rp,
                                            const float* __restrict__ g,
                                            const float* __restrict__ b, int c16) {
    return ln_unpack_core(*(const uint4*)rp, g, b, c16);
}

// ---------- MEGA v2: conv x4 + attn-LN + QKV. 100-token chunks, grid 256 = 1 block/CU ----------
// LDS XOR-swizzled (16B block ^ (row&7)) so all b128 A-reads are conflict-free.
// L: 124 rows (12-halo each side). R: rows 3..120 (stored offset -3).

#define LROWS 124
#define RROWS 118

__global__ __launch_bounds__(512) void mega(const float* __restrict__ x,
                                            const float* __restrict__ pe,
                                            const unsigned short* __restrict__ mwf,
                                            const float* __restrict__ mb,
                                            const float* __restrict__ ln_g,
                                            const float* __restrict__ ln_b,
                                            const float* __restrict__ attg,
                                            const float* __restrict__ attb,
                                            const unsigned short* __restrict__ wfb,
                                            const float* __restrict__ bq,
                                            const float* __restrict__ bk,
                                            const float* __restrict__ bv,
                                            unsigned short* __restrict__ Qo,
                                            unsigned short* __restrict__ Ko,
                                            unsigned short* __restrict__ Vo) {
    __shared__ unsigned short Lf[LROWS * 128];
    __shared__ unsigned short Rf[RROWS * 128];
    int tid = threadIdx.x, lane = tid & 63, w = tid >> 6;
    int bI = blockIdx.x >> 2;
    int s0 = (blockIdx.x & 3) * 100;
    int arow = lane & 15, h = lane >> 4, rr = h * 4;
    int nb0 = (w & 3) * 2, mh = w >> 2;

    // ---- layer-0 LN fill from global f32 (x + pe), rows [0,124) ----
    for (int c = tid; c < LROWS * 16; c += 512) {
        int idx = c >> 4, c16 = c & 15;
        int g = s0 - 12 + idx;
        uint4 o = make_uint4(0u, 0u, 0u, 0u);
        if (g >= 0 && g < Ss) {
            const float* rp = x + ((size_t)bI * Ss + g) * Dm + c16 * 8;
            const float* pp = pe + (size_t)g * Dm + c16 * 8;
            float v[8];
            #pragma unroll
            for (int j = 0; j < 8; ++j) v[j] = rp[j] + pp[j];
            o = ln_core(v, ln_g, ln_b, c16);
        }
        *(uint4*)(Lf + idx * 128 + ((c16 ^ (idx & 7)) << 3)) = o;
    }
    __syncthreads();

    // ---- 4 conv layers: L -> conv -> R -> LN -> L ----
    const int NT[4] = {8, 7, 7, 7};
    for (int l = 0; l < 4; ++l) {
        int in_lo = 3 * l;
        int out_lo = 3 * (l + 1), out_hi = LROWS - 3 * (l + 1);
        int ntiles = NT[l];
        const unsigned short* mw = mwf + (size_t)l * 114688;

        f32x4 acc[2][4];
        #pragma unroll
        for (int n = 0; n < 2; ++n)
            #pragma unroll
            for (int mi = 0; mi < 4; ++mi) acc[n][mi] = (f32x4){0.f, 0.f, 0.f, 0.f};

        #pragma unroll 4
        for (int kb = 0; kb < 28; ++kb) {
            int k = kb >> 2, blk0 = (kb & 3) * 4 + h;
            bf16x8 b0 = *(const bf16x8*)(mw + ((size_t)(kb * 8 + nb0)) * 512 + lane * 8);
            bf16x8 b1 = *(const bf16x8*)(mw + ((size_t)(kb * 8 + nb0 + 1)) * 512 + lane * 8);
            #pragma unroll
            for (int mi = 0; mi < 4; ++mi) {
                int m = mh + 2 * mi;
                if (m < ntiles) {
                    int ar = in_lo + m * 16 + arow + k;
                    if (ar > LROWS - 1) ar = LROWS - 1;
                    bf16x8 af = *(const bf16x8*)(Lf + ar * 128 + ((blk0 ^ (ar & 7)) << 3));
                    acc[0][mi] = __builtin_amdgcn_mfma_f32_16x16x32_bf16(af, b0, acc[0][mi], 0, 0, 0);
                    acc[1][mi] = __builtin_amdgcn_mfma_f32_16x16x32_bf16(af, b1, acc[1][mi], 0, 0, 0);
                }
            }
        }
        // write conv outputs to R (swizzled), then barrier
        #pragma unroll
        for (int n = 0; n < 2; ++n) {
            int f = (nb0 + n) * 16 + arow;
            int fblk = f >> 3, flo = f & 7;
            float bias = mb[l * Dm + f];
            #pragma unroll
            for (int mi = 0; mi < 4; ++mi) {
                int m = mh + 2 * mi;
                if (m < ntiles) {
                    #pragma unroll
                    for (int r = 0; r < 4; ++r) {
                        int o = out_lo + m * 16 + rr + r;
                        if (o < out_hi) {
                            int rw = o - 3;
                            Rf[rw * 128 + ((fblk ^ (rw & 7)) << 3) + flo] = f2bf(acc[n][mi][r] + bias);
                        }
                    }
                }
            }
        }
        __syncthreads();

        // LN refill of L
        if (l < 3) {
            const float* lg = ln_g + (l + 1) * Dm;
            const float* lb = ln_b + (l + 1) * Dm;
            int span = out_hi - out_lo;
            for (int c = tid; c < span * 16; c += 512) {
                int idx = out_lo + (c >> 4), c16 = c & 15;
                int g = s0 - 12 + idx;
                uint4 o = make_uint4(0u, 0u, 0u, 0u);
                if (g >= 0 && g < Ss) {
                    int rw = idx - 3;
                    uint4 u = *(const uint4*)(Rf + rw * 128 + ((c16 ^ (rw & 7)) << 3));
                    o = ln_unpack_core(u, lg, lb, c16);
                }
                *(uint4*)(Lf + idx * 128 + ((c16 ^ (idx & 7)) << 3)) = o;
            }
        } else {
            for (int c = tid; c < 100 * 16; c += 512) {
                int idx = 12 + (c >> 4), c16 = c & 15;
                int rw = idx - 3;
                uint4 u = *(const uint4*)(Rf + rw * 128 + ((c16 ^ (rw & 7)) << 3));
                *(uint4*)(Lf + idx * 128 + ((c16 ^ (idx & 7)) << 3)) = ln_unpack_core(u, attg, attb, c16);
            }
        }
        __syncthreads();
    }

    // ---- QKV projections from L rows [12,112): 7 m-tiles, 100 tokens ----
    for (int mat = 0; mat < 3; ++mat) {
        const unsigned short* wf = wfb + (size_t)mat * 16384;
        f32x4 acc[2][4];
        #pragma unroll
        for (int n = 0; n < 2; ++n)
            #pragma unroll
            for (int mi = 0; mi < 4; ++mi) acc[n][mi] = (f32x4){0.f, 0.f, 0.f, 0.f};
        #pragma unroll
        for (int kb = 0; kb < 4; ++kb) {
            int blk0 = kb * 4 + h;
            bf16x8 b0 = *(const bf16x8*)(wf + ((size_t)(kb * 8 + nb0)) * 512 + lane * 8);
            bf16x8 b1 = *(const bf16x8*)(wf + ((size_t)(kb * 8 + nb0 + 1)) * 512 + lane * 8);
            #pragma unroll
            for (int mi = 0; mi < 4; ++mi) {
                int m = mh + 2 * mi;
                if (m < 7) {
                    int ar = 12 + m * 16 + arow;
                    bf16x8 af = *(const bf16x8*)(Lf + ar * 128 + ((blk0 ^ (ar & 7)) << 3));
                    acc[0][mi] = __builtin_amdgcn_mfma_f32_16x16x32_bf16(af, b0, acc[0][mi], 0, 0, 0);
                    acc[1][mi] = __builtin_amdgcn_mfma_f32_16x16x32_bf16(af, b1, acc[1][mi], 0, 0, 0);
                }
            }
        }
        const float* bias = (mat == 0) ? bq : (mat == 1) ? bk : bv;
        float sc = (mat == 0) ? 0.25f : 1.0f;
        #pragma unroll
        for (int n = 0; n < 2; ++n) {
            int hI = nb0 + n;
            float bvv = bias[hI * 16 + arow];
            if (mat < 2) {
                unsigned short* qo = (mat == 0) ? Qo : Ko;
                #pragma unroll
                for (int mi = 0; mi < 4; ++mi) {
                    int m = mh + 2 * mi;
                    if (m < 7) {
                        #pragma unroll
                        for (int r = 0; r < 4; ++r) {
                            int lcl = m * 16 + rr + r;
                            if (lcl < 100) {
                                int s = s0 + lcl;
                                qo[(((size_t)(bI * Hh + hI)) * Ss + s) * 16 + arow] =
                                    f2bf((acc[n][mi][r] + bvv) * sc);
                            }
                        }
                    }
                }
            } else {
                unsigned short* base = Vo + ((size_t)(bI * Hh + hI) * 16 + arow) * SsP + s0;
                #pragma unroll
                for (int mi = 0; mi < 4; ++mi) {
                    int m = mh + 2 * mi;
                    int lcl = m * 16 + rr;
                    if (m < 7 && lcl < 100) {
                        unsigned lo = packbf(acc[n][mi][0] + bvv, acc[n][mi][1] + bvv);
                        unsigned hi = packbf(acc[n][mi][2] + bvv, acc[n][mi][3] + bvv);
                        *(uint2*)(base + lcl) = make_uint2(lo, hi);
                    }
                }
            }
        }
    }
}

// ---------- generic token GEMM: bf16 in (opt LN); mode 0: bf16 out, 1: f32 relu out ----------

__global__ __launch_bounds__(256) void gemm2(const unsigned short* __restrict__ in,
                                             const unsigned short* __restrict__ wf,
                                             const float* __restrict__ bias,
                                             const float* __restrict__ lng,
                                             const float* __restrict__ lnb,
                                             void* __restrict__ outv, int mode) {
    __shared__ unsigned short hs[80][136];
    int tid = threadIdx.x;
    int lane = tid & 63, w = tid >> 6;
    size_t tok0 = (size_t)blockIdx.x * 80;
    const unsigned short* ib = in + tok0 * Dm;
    if (lng) {
        for (int c = tid; c < 80 * 16; c += 256) {
            int row = c >> 4, c16 = c & 15;
            *(uint4*)&hs[row][c16 * 8] = ln_pack_bf(ib + (size_t)row * Dm + c16 * 8, lng, lnb, c16);
        }
    } else {
        for (int c = tid; c < 80 * 16; c += 256) {
            int row = c >> 4, c16 = c & 15;
            *(uint4*)&hs[row][c16 * 8] = *(const uint4*)(ib + (size_t)row * Dm + c16 * 8);
        }
    }
    __syncthreads();

    f32x4 acc[2][5];
    #pragma unroll
    for (int n = 0; n < 2; ++n)
        #pragma unroll
        for (int m = 0; m < 5; ++m) acc[n][m] = (f32x4){0.f, 0.f, 0.f, 0.f};

    int nb0 = w * 2;
    int arow = lane & 15, acol = (lane >> 4) * 8;
    #pragma unroll
    for (int kb = 0; kb < 4; ++kb) {
        bf16x8 b0 = *(const bf16x8*)(wf + ((size_t)(kb * 8 + nb0)) * 512 + lane * 8);
        bf16x8 b1 = *(const bf16x8*)(wf + ((size_t)(kb * 8 + nb0 + 1)) * 512 + lane * 8);
        #pragma unroll
        for (int m = 0; m < 5; ++m) {
            bf16x8 af = *(const bf16x8*)&hs[m * 16 + arow][kb * 32 + acol];
            acc[0][m] = __builtin_amdgcn_mfma_f32_16x16x32_bf16(af, b0, acc[0][m], 0, 0, 0);
            acc[1][m] = __builtin_amdgcn_mfma_f32_16x16x32_bf16(af, b1, acc[1][m], 0, 0, 0);
        }
    }
    int rr = (lane >> 4) * 4;
    #pragma unroll
    for (int n = 0; n < 2; ++n) {
        int f0 = (nb0 + n) * 16;
        float bvv = bias[f0 + arow];
        #pragma unroll
        for (int m = 0; m < 5; ++m)
            #pragma unroll
            for (int r = 0; r < 4; ++r) {
                float v = acc[n][m][r] + bvv;
                if (mode == 1) {
                    ((float*)outv)[(tok0 + m * 16 + rr + r) * Dm + f0 + arow] = fmaxf(v, 0.f);
                } else {
                    ((unsigned short*)outv)[(tok0 + m * 16 + rr + r) * Dm + f0 + arow] = f2bf(v);
                }
            }
    }
}

// ---------- flash attention: block = one (b,h), 5 waves = 5 q-tiles (K/V L1-shared) ----------

__global__ __launch_bounds__(320) void attn_mfma(const unsigned short* __restrict__ Q,
                                                 const unsigned short* __restrict__ Kb,
                                                 const unsigned short* __restrict__ VT,
                                                 unsigned short* __restrict__ out) {
    int wid = threadIdx.x >> 6, lane = threadIdx.x & 63;
    int bh = blockIdx.x;                     // 512
    int qt = blockIdx.y * 5 + wid;           // 0..24
    int q15 = lane & 15, h = lane >> 4;
    int qg = qt * 16 + q15;

    uint4 qv = make_uint4(0u, 0u, 0u, 0u);
    if (h < 2) qv = *(const uint4*)(Q + ((size_t)bh * Ss + qg) * 16 + h * 8);
    bf16x8 qf = __builtin_bit_cast(bf16x8, qv);

    f32x4 o = (f32x4){0.f, 0.f, 0.f, 0.f};
    float mrow = -1e30f, lrow = 0.f;
    const unsigned short* kbase = Kb + (size_t)bh * Ss * 16;
    const unsigned short* vbase = VT + ((size_t)bh * 16 + q15) * SsP;
    int srcA = q15 + ((h & 1) << 5);
    int srcB = srcA + 16;
    bool t1 = h >= 2;
    f32x4 z = (f32x4){0.f, 0.f, 0.f, 0.f};

    for (int kt0 = 0; kt0 <= qt; kt0 += 4) {     // 64 k per chunk
        uint4 kv[4];
        #pragma unroll
        for (int t = 0; t < 4; ++t) {
            kv[t] = make_uint4(0u, 0u, 0u, 0u);
            if (h < 2 && kt0 + t <= qt)
                kv[t] = *(const uint4*)(kbase + (size_t)((kt0 + t) * 16 + q15) * 16 + h * 8);
        }
        f32x4 s[4];
        #pragma unroll
        for (int t = 0; t < 4; ++t)
            s[t] = __builtin_amdgcn_mfma_f32_16x16x32_bf16(__builtin_bit_cast(bf16x8, kv[t]), qf, z, 0, 0, 0);

        float p[16];
        #pragma unroll
        for (int t = 0; t < 4; ++t)
            #pragma unroll
            for (int r = 0; r < 4; ++r) {
                int ka = (kt0 + t) * 16 + h * 4 + r;
                p[t * 4 + r] = (ka <= qg) ? s[t][r] : -1e30f;
            }
        float tm = p[0];
        #pragma unroll
        for (int i = 1; i < 16; ++i) tm = fmaxf(tm, p[i]);
        tm = fmaxf(tm, __shfl_xor(tm, 16));
        tm = fmaxf(tm, __shfl_xor(tm, 32));
        float mnew = fmaxf(mrow, tm);
        float corr = __expf(mrow - mnew);
        float psum = 0.f;
        #pragma unroll
        for (int i = 0; i < 16; ++i) { p[i] = __expf(p[i] - mnew); psum += p[i]; }
        psum += __shfl_xor(psum, 16);
        psum += __shfl_xor(psum, 32);
        lrow = lrow * corr + psum;
        mrow = mnew;
        o[0] *= corr; o[1] *= corr; o[2] *= corr; o[3] *= corr;

        #pragma unroll
        for (int pr = 0; pr < 2; ++pr) {
            const float* pp = p + pr * 8;
            unsigned pk0 = packbf(pp[0], pp[1]), pk1 = packbf(pp[2], pp[3]);
            unsigned pk2 = packbf(pp[4], pp[5]), pk3 = packbf(pp[6], pp[7]);
            unsigned a0 = __shfl(pk0, srcA), a1 = __shfl(pk1, srcA);
            unsigned a2 = __shfl(pk0, srcB), a3 = __shfl(pk1, srcB);
            unsigned b0 = __shfl(pk2, srcA), b1 = __shfl(pk3, srcA);
            unsigned b2 = __shfl(pk2, srcB), b3 = __shfl(pk3, srcB);
            uint4 pw = make_uint4(t1 ? b0 : a0, t1 ? b1 : a1, t1 ? b2 : a2, t1 ? b3 : a3);
            uint4 vv = *(const uint4*)(vbase + (kt0 + pr * 2) * 16 + h * 8);
            o = __builtin_amdgcn_mfma_f32_16x16x32_bf16(__builtin_bit_cast(bf16x8, vv),
                                                        __builtin_bit_cast(bf16x8, pw), o, 0, 0, 0);
        }
    }
    float inv = 1.0f / lrow;
    int bI = bh >> 3, hh = bh & 7;
    unsigned short* op = out + ((size_t)bI * Ss + qg) * Dm + hh * 16 + h * 4;
    *(uint2*)op = make_uint2(packbf(o[0] * inv, o[1] * inv),
                             packbf(o[2] * inv, o[3] * inv));
}

// ---------- launch ----------

extern "C" void kernel_launch(void* const* d_in, const int* in_sizes, int n_in,
                              void* d_out, int out_size, void* d_ws, size_t ws_size,
                              hipStream_t stream) {
    (void)in_sizes; (void)n_in; (void)out_size; (void)ws_size;
    const float* x       = (const float*)d_in[0];
    const float* ln_g    = (const float*)d_in[1];
    const float* ln_b    = (const float*)d_in[2];
    const float* dw_w    = (const float*)d_in[3];
    const float* dw_b    = (const float*)d_in[4];
    const float* pw_w    = (const float*)d_in[5];
    const float* pw_b    = (const float*)d_in[6];
    const float* attln_g = (const float*)d_in[7];
    const float* attln_b = (const float*)d_in[8];
    const float* wq = (const float*)d_in[9];
    const float* bq = (const float*)d_in[10];
    const float* wk = (const float*)d_in[11];
    const float* bk = (const float*)d_in[12];
    const float* wv = (const float*)d_in[13];
    const float* bv = (const float*)d_in[14];
    const float* wp = (const float*)d_in[15];
    const float* bp = (const float*)d_in[16];
    const float* ffnln_g = (const float*)d_in[17];
    const float* ffnln_b = (const float*)d_in[18];
    const float* fc_w = (const float*)d_in[19];
    const float* fc_b = (const float*)d_in[20];

    float* ws = (float*)d_ws;
    float* pe = ws;                                      // 51200 f
    float* mb = pe + 51200;                              // 512 f
    unsigned short* mwf = (unsigned short*)(mb + 512);   // 458752 u16
    unsigned short* wfb = mwf + 458752;                  // 81920 u16
    unsigned short* Qb  = wfb + 81920;                   // 3276800 u16
    unsigned short* Kb2 = Qb + 3276800;                  // 3276800 u16
    unsigned short* VTb = Kb2 + 3276800;                 // 512*16*448 = 3670016 u16
    unsigned short* A1b = VTb + 3670016;                 // 3276800 u16
    unsigned short* C1  = A1b + 3276800;                 // 3276800 u16

    prep_all<<<580, 256, 0, stream>>>(wq, wk, wv, wp, fc_w, pw_w, dw_w, dw_b, pw_b,
                                      pe, wfb, mb, mwf);

    // conv x4 + attn-LN + QKV in one dispatch (grid 256 = 1 block/CU)
    mega<<<256, 512, 0, stream>>>(x, pe, mwf, mb, ln_g, ln_b, attln_g, attln_b,
                                  wfb, bq, bk, bv, Qb, Kb2, VTb);

    attn_mfma<<<dim3(512, 5), 320, 0, stream>>>(Qb, Kb2, VTb, A1b);
    gemm2<<<320, 256, 0, stream>>>(A1b, wfb + 3 * 16384, bp, nullptr, nullptr, C1, 0);

    // ffn (LN inline, relu out f32)
    gemm2<<<320, 256, 0, stream>>>(C1, wfb + 4 * 16384, fc_b, ffnln_g, ffnln_b, d_out, 1);
}

// Round 13
// 119.602 us; speedup vs baseline: 1.0605x; 1.0605x over previous
//
#include <hip/hip_runtime.h>
#include <hip/hip_bf16.h>
#include <math.h>

#define Dm 128
#define Lc 4
#define Kc 7
#define Hh 8
#define Bb 64
#define Ss 400
#define SsP 448
#define TOK (Bb*Ss)

typedef __attribute__((ext_vector_type(8))) short bf16x8;
typedef __attribute__((ext_vector_type(4))) float f32x4;

__device__ __forceinline__ float bf2f(unsigned int u) {
    union { unsigned int i; float f; } x; x.i = u << 16; return x.f;
}
__device__ __forceinline__ unsigned short f2bf(float f) {
    __hip_bfloat16 h = __float2bfloat16(f);
    return __builtin_bit_cast(unsigned short, h);
}
__device__ __forceinline__ unsigned int packbf(float a, float b) {
    return (unsigned int)f2bf(a) | ((unsigned int)f2bf(b) << 16);
}

// ---------- fused prep: pe (200) + repack_w (320) + merge_bias (4) + merge_conv (56) ----------

__global__ __launch_bounds__(256) void prep_all(const float* __restrict__ wq, const float* __restrict__ wk,
                                                const float* __restrict__ wv, const float* __restrict__ wp,
                                                const float* __restrict__ fc,
                                                const float* __restrict__ pw_w, const float* __restrict__ dw_w,
                                                const float* __restrict__ dw_b, const float* __restrict__ pw_b,
                                                float* __restrict__ pe, unsigned short* __restrict__ wf,
                                                float* __restrict__ mb, unsigned short* __restrict__ mwf) {
    __shared__ unsigned short hiS[64][136];
    __shared__ unsigned short loS[64][136];
    int blk = blockIdx.x;
    int tid = threadIdx.x;
    if (blk < 200) {
        int s = blk * 2 + (tid >> 7);
        int c = tid & 127;
        int j = (c < 64) ? c : (c - 64);
        float freq = expf(-(2.0f * j / 128.0f) * 9.210340371976184f);
        float a = (float)s * freq;
        pe[s * Dm + c] = (c < 64) ? sinf(a) : cosf(a);
        return;
    }
    if (blk < 520) {
        int idx = (blk - 200) * 256 + tid;
        int m = idx >> 14;
        int r = idx & 16383;
        int fragi = r >> 9, lr = (r >> 3) & 63, j = r & 7;
        int kb = fragi >> 3, nb = fragi & 7;
        int o = nb * 16 + (lr & 15);
        int d = kb * 32 + (lr >> 4) * 8 + j;
        const float* src = (m == 0) ? wq : (m == 1) ? wk : (m == 2) ? wv : (m == 3) ? wp : fc;
        wf[idx] = f2bf(src[o * Dm + d]);
        return;
    }
    if (blk < 524) {
        int l = blk - 520;
        int f = tid;
        if (f < Dm) {
            const float* pwl = pw_w + ((size_t)l * Dm + f) * Dm;
            const float* db  = dw_b + l * Dm;
            float acc = pw_b[l * Dm + f];
            #pragma unroll 8
            for (int c4 = 0; c4 < 32; ++c4) {
                float4 p = *(const float4*)(pwl + c4 * 4);
                float4 d = *(const float4*)(db + c4 * 4);
                acc += p.x * d.x + p.y * d.y + p.z * d.z + p.w * d.w;
            }
            mb[l * Dm + f] = acc;
        }
        return;
    }
    int mblk = blk - 524;
    int ih = mblk & 1;
    int k  = (mblk >> 1) % 7;
    int l  = mblk / 14;
    int lane = tid & 63, w = tid >> 6;

    const float* dwl = dw_w + (size_t)l * (Dm * Dm * Kc) + k;
    for (int it = 0; it < 32; ++it) {
        int idx = it * 256 + tid;
        int c = idx >> 6, il = idx & 63;
        int i = ih * 64 + il;
        float x = dwl[(size_t)(c * Dm + i) * Kc];
        unsigned short hi = f2bf(x);
        float lo = x - bf2f(hi);
        hiS[il][c] = hi;
        loS[il][c] = f2bf(lo);
    }
    __syncthreads();

    const float* pwl = pw_w + (size_t)l * Dm * Dm;
    int arow = lane & 15, ac = (lane >> 4) * 8;
    f32x4 acc[2][4];
    #pragma unroll
    for (int n = 0; n < 2; ++n)
        #pragma unroll
        for (int m = 0; m < 4; ++m) acc[n][m] = (f32x4){0.f, 0.f, 0.f, 0.f};

    #pragma unroll
    for (int kb = 0; kb < 4; ++kb) {
        int c0 = kb * 32 + ac;
        bf16x8 Bhi[2], Blo[2];
        #pragma unroll
        for (int n = 0; n < 2; ++n) {
            int f = (w * 2 + n) * 16 + arow;
            const float* rp = pwl + (size_t)f * Dm + c0;
            float4 a = *(const float4*)rp;
            float4 b = *(const float4*)(rp + 4);
            float v[8] = {a.x, a.y, a.z, a.w, b.x, b.y, b.z, b.w};
            unsigned short hh[8], ll[8];
            #pragma unroll
            for (int j = 0; j < 8; ++j) {
                hh[j] = f2bf(v[j]);
                ll[j] = f2bf(v[j] - bf2f(hh[j]));
            }
            uint4 uh = make_uint4((unsigned)hh[0] | ((unsigned)hh[1] << 16),
                                  (unsigned)hh[2] | ((unsigned)hh[3] << 16),
                                  (unsigned)hh[4] | ((unsigned)hh[5] << 16),
                                  (unsigned)hh[6] | ((unsigned)hh[7] << 16));
            uint4 ul = make_uint4((unsigned)ll[0] | ((unsigned)ll[1] << 16),
                                  (unsigned)ll[2] | ((unsigned)ll[3] << 16),
                                  (unsigned)ll[4] | ((unsigned)ll[5] << 16),
                                  (unsigned)ll[6] | ((unsigned)ll[7] << 16));
            Bhi[n] = __builtin_bit_cast(bf16x8, uh);
            Blo[n] = __builtin_bit_cast(bf16x8, ul);
        }
        #pragma unroll
        for (int m = 0; m < 4; ++m) {
            bf16x8 ahi = *(const bf16x8*)&hiS[m * 16 + arow][c0];
            bf16x8 alo = *(const bf16x8*)&loS[m * 16 + arow][c0];
            #pragma unroll
            for (int n = 0; n < 2; ++n) {
                acc[n][m] = __builtin_amdgcn_mfma_f32_16x16x32_bf16(ahi, Bhi[n], acc[n][m], 0, 0, 0);
                acc[n][m] = __builtin_amdgcn_mfma_f32_16x16x32_bf16(ahi, Blo[n], acc[n][m], 0, 0, 0);
                acc[n][m] = __builtin_amdgcn_mfma_f32_16x16x32_bf16(alo, Bhi[n], acc[n][m], 0, 0, 0);
            }
        }
    }
    #pragma unroll
    for (int n = 0; n < 2; ++n) {
        int nb = w * 2 + n;
        #pragma unroll
        for (int m = 0; m < 4; ++m) {
            int i0 = ih * 64 + m * 16 + (lane >> 4) * 4;
            int ib = i0 >> 5, i32 = i0 & 31;
            int lanep = ((i32 >> 3) << 4) | arow;
            int jb = i32 & 7;
            size_t frag = ((size_t)(l * 28 + (k * 4 + ib)) * 8 + nb);
            *(uint2*)(mwf + frag * 512 + lanep * 8 + jb) =
                make_uint2(packbf(acc[n][m][0], acc[n][m][1]),
                           packbf(acc[n][m][2], acc[n][m][3]));
        }
    }
}

// ---------- LN helpers ----------

__device__ __forceinline__ uint4 ln_core(float v[8],
                                         const float* __restrict__ g,
                                         const float* __restrict__ b, int c16) {
    float sum = 0.f, sq = 0.f;
    #pragma unroll
    for (int j = 0; j < 8; ++j) { sum += v[j]; sq += v[j] * v[j]; }
    #pragma unroll
    for (int off = 8; off; off >>= 1) {
        sum += __shfl_xor(sum, off);
        sq  += __shfl_xor(sq, off);
    }
    float mu = sum * (1.0f / 128.0f);
    float var = sq * (1.0f / 128.0f) - mu * mu;
    float rs = rsqrtf(var + 1e-5f);
    float4 g0 = *(const float4*)(g + c16 * 8);
    float4 g1 = *(const float4*)(g + c16 * 8 + 4);
    float4 b0 = *(const float4*)(b + c16 * 8);
    float4 b1 = *(const float4*)(b + c16 * 8 + 4);
    uint4 o;
    o.x = packbf((v[0] - mu) * rs * g0.x + b0.x, (v[1] - mu) * rs * g0.y + b0.y);
    o.y = packbf((v[2] - mu) * rs * g0.z + b0.z, (v[3] - mu) * rs * g0.w + b0.w);
    o.z = packbf((v[4] - mu) * rs * g1.x + b1.x, (v[5] - mu) * rs * g1.y + b1.y);
    o.w = packbf((v[6] - mu) * rs * g1.z + b1.z, (v[7] - mu) * rs * g1.w + b1.w);
    return o;
}

__device__ __forceinline__ uint4 ln_pack_bf(const unsigned short* __restrict__ rp,
                                            const float* __restrict__ g,
                                            const float* __restrict__ b, int c16) {
    uint4 u = *(const uint4*)rp;
    float v[8] = { bf2f(u.x & 0xffffu), bf2f(u.x >> 16), bf2f(u.y & 0xffffu), bf2f(u.y >> 16),
                   bf2f(u.z & 0xffffu), bf2f(u.z >> 16), bf2f(u.w & 0xffffu), bf2f(u.w >> 16) };
    return ln_core(v, g, b, c16);
}

// ---------- conv (R7-proven): M=48/block, 8 waves x (1nb x 3m), bf16 act ----------
// blockIdx XOR-free bijective XCD swizzle: 576 blocks, 576%8==0.

__global__ __launch_bounds__(512) void conv_mfma(const unsigned short* __restrict__ in16,
                                                 const float* __restrict__ in32,
                                                 const float* __restrict__ pe,
                                                 const unsigned short* __restrict__ mwf,
                                                 const float* __restrict__ mb,
                                                 const float* __restrict__ lng,
                                                 const float* __restrict__ lnb,
                                                 unsigned short* __restrict__ out) {
    __shared__ unsigned short hs[54][136];
    int tid = threadIdx.x;
    int lane = tid & 63, w = tid >> 6;
    int swz = (blockIdx.x & 7) * 72 + (blockIdx.x >> 3);   // bijection on [0,576)
    int bI = swz / 9;
    int st = swz % 9;
    int s0 = st * 48;
    for (int c = tid; c < 54 * 16; c += 512) {
        int row = c >> 4, c16 = c & 15;
        int gs = s0 - 3 + row;
        uint4 o = make_uint4(0u, 0u, 0u, 0u);
        if (gs >= 0 && gs < Ss) {
            if (in32) {
                const float* rp = in32 + ((size_t)bI * Ss + gs) * Dm + c16 * 8;
                const float* pp = pe + (size_t)gs * Dm + c16 * 8;
                float v[8];
                #pragma unroll
                for (int j = 0; j < 8; ++j) v[j] = rp[j] + pp[j];
                o = ln_core(v, lng, lnb, c16);
            } else {
                o = ln_pack_bf(in16 + ((size_t)bI * Ss + gs) * Dm + c16 * 8, lng, lnb, c16);
            }
        }
        *(uint4*)&hs[row][c16 * 8] = o;
    }
    __syncthreads();

    f32x4 acc[3];
    #pragma unroll
    for (int m = 0; m < 3; ++m) acc[m] = (f32x4){0.f, 0.f, 0.f, 0.f};

    int nb = w;
    int arow = lane & 15, acol = (lane >> 4) * 8;
    #pragma unroll 4
    for (int kb = 0; kb < 28; ++kb) {
        int k = kb >> 2, i0 = (kb & 3) * 32;
        bf16x8 bfr = *(const bf16x8*)(mwf + ((size_t)(kb * 8 + nb)) * 512 + lane * 8);
        #pragma unroll
        for (int m = 0; m < 3; ++m) {
            bf16x8 af = *(const bf16x8*)&hs[m * 16 + arow + k][i0 + acol];
            acc[m] = __builtin_amdgcn_mfma_f32_16x16x32_bf16(af, bfr, acc[m], 0, 0, 0);
        }
    }
    int rr = (lane >> 4) * 4;
    int f0 = nb * 16;
    float bias = mb[f0 + arow];
    #pragma unroll
    for (int m = 0; m < 3; ++m)
        #pragma unroll
        for (int r = 0; r < 4; ++r) {
            int s = s0 + m * 16 + rr + r;
            if (s < Ss)
                out[((size_t)bI * Ss + s) * Dm + f0 + arow] = f2bf(acc[m][r] + bias);
        }
}

// ---------- fused QKV (R7-proven): grid (320, 2). y=0: Q+K; y=1: V^T ----------

__global__ __launch_bounds__(256) void qkv_mfma(const unsigned short* __restrict__ in,
                                                const float* __restrict__ lng,
                                                const float* __restrict__ lnb,
                                                const unsigned short* __restrict__ wfb,
                                                const float* __restrict__ bq,
                                                const float* __restrict__ bk,
                                                const float* __restrict__ bv,
                                                unsigned short* __restrict__ Qo,
                                                unsigned short* __restrict__ Ko,
                                                unsigned short* __restrict__ Vo) {
    __shared__ unsigned short hs[80][136];
    int tid = threadIdx.x;
    int lane = tid & 63, w = tid >> 6;
    int y = blockIdx.y;
    int swz = (blockIdx.x & 7) * 40 + (blockIdx.x >> 3);   // bijection on [0,320)
    int bI = swz / 5;
    int sb = (swz % 5) * 80;
    const unsigned short* ib = in + ((size_t)bI * Ss + sb) * Dm;
    for (int c = tid; c < 80 * 16; c += 256) {
        int row = c >> 4, c16 = c & 15;
        *(uint4*)&hs[row][c16 * 8] = ln_pack_bf(ib + (size_t)row * Dm + c16 * 8, lng, lnb, c16);
    }
    __syncthreads();

    int nb0 = w * 2;
    int arow = lane & 15, acol = (lane >> 4) * 8;
    int nmat = (y == 0) ? 2 : 1;
    for (int mi = 0; mi < nmat; ++mi) {
        int mat = (y == 0) ? mi : 2;
        const unsigned short* wf = wfb + (size_t)mat * 16384;
        f32x4 acc[2][5];
        #pragma unroll
        for (int n = 0; n < 2; ++n)
            #pragma unroll
            for (int m = 0; m < 5; ++m) acc[n][m] = (f32x4){0.f, 0.f, 0.f, 0.f};
        #pragma unroll
        for (int kb = 0; kb < 4; ++kb) {
            bf16x8 b0 = *(const bf16x8*)(wf + ((size_t)(kb * 8 + nb0)) * 512 + lane * 8);
            bf16x8 b1 = *(const bf16x8*)(wf + ((size_t)(kb * 8 + nb0 + 1)) * 512 + lane * 8);
            #pragma unroll
            for (int m = 0; m < 5; ++m) {
                bf16x8 af = *(const bf16x8*)&hs[m * 16 + arow][kb * 32 + acol];
                acc[0][m] = __builtin_amdgcn_mfma_f32_16x16x32_bf16(af, b0, acc[0][m], 0, 0, 0);
                acc[1][m] = __builtin_amdgcn_mfma_f32_16x16x32_bf16(af, b1, acc[1][m], 0, 0, 0);
            }
        }
        int rr = (lane >> 4) * 4;
        const float* bias = (mat == 0) ? bq : (mat == 1) ? bk : bv;
        float sc = (mat == 0) ? 0.25f : 1.0f;
        #pragma unroll
        for (int n = 0; n < 2; ++n) {
            int hI = nb0 + n;
            float bvv = bias[hI * 16 + arow];
            if (mat < 2) {
                unsigned short* qo = (mat == 0) ? Qo : Ko;
                #pragma unroll
                for (int m = 0; m < 5; ++m)
                    #pragma unroll
                    for (int r = 0; r < 4; ++r) {
                        int s = sb + m * 16 + rr + r;
                        qo[(((size_t)(bI * Hh + hI)) * Ss + s) * 16 + arow] = f2bf((acc[n][m][r] + bvv) * sc);
                    }
            } else {
                unsigned short* base = Vo + ((size_t)(bI * Hh + hI) * 16 + arow) * SsP + sb;
                #pragma unroll
                for (int m = 0; m < 5; ++m) {
                    unsigned lo = packbf(acc[n][m][0] + bvv, acc[n][m][1] + bvv);
                    unsigned hi = packbf(acc[n][m][2] + bvv, acc[n][m][3] + bvv);
                    *(uint2*)(base + m * 16 + rr) = make_uint2(lo, hi);
                }
            }
        }
    }
}

// ---------- flash attention (R9-proven): shuffle P-repack, online-max, 64-k chunks ----------

__global__ __launch_bounds__(320) void attn_mfma(const unsigned short* __restrict__ Q,
                                                 const unsigned short* __restrict__ Kb,
                                                 const unsigned short* __restrict__ VT,
                                                 unsigned short* __restrict__ out) {
    int wid = threadIdx.x >> 6, lane = threadIdx.x & 63;
    int bh = (blockIdx.x & 7) * 64 + (blockIdx.x >> 3);   // bijection on [0,512)
    int qt = blockIdx.y * 5 + wid;           // 0..24
    int q15 = lane & 15, h = lane >> 4;
    int qg = qt * 16 + q15;

    uint4 qv = make_uint4(0u, 0u, 0u, 0u);
    if (h < 2) qv = *(const uint4*)(Q + ((size_t)bh * Ss + qg) * 16 + h * 8);
    bf16x8 qf = __builtin_bit_cast(bf16x8, qv);

    f32x4 o = (f32x4){0.f, 0.f, 0.f, 0.f};
    float mrow = -1e30f, lrow = 0.f;
    const unsigned short* kbase = Kb + (size_t)bh * Ss * 16;
    const unsigned short* vbase = VT + ((size_t)bh * 16 + q15) * SsP;
    int srcA = q15 + ((h & 1) << 5);
    int srcB = srcA + 16;
    bool t1 = h >= 2;
    f32x4 z = (f32x4){0.f, 0.f, 0.f, 0.f};

    for (int kt0 = 0; kt0 <= qt; kt0 += 4) {     // 64 k per chunk
        uint4 kv[4];
        #pragma unroll
        for (int t = 0; t < 4; ++t) {
            kv[t] = make_uint4(0u, 0u, 0u, 0u);
            if (h < 2 && kt0 + t <= qt)
                kv[t] = *(const uint4*)(kbase + (size_t)((kt0 + t) * 16 + q15) * 16 + h * 8);
        }
        f32x4 s[4];
        #pragma unroll
        for (int t = 0; t < 4; ++t)
            s[t] = __builtin_amdgcn_mfma_f32_16x16x32_bf16(__builtin_bit_cast(bf16x8, kv[t]), qf, z, 0, 0, 0);

        float p[16];
        #pragma unroll
        for (int t = 0; t < 4; ++t)
            #pragma unroll
            for (int r = 0; r < 4; ++r) {
                int ka = (kt0 + t) * 16 + h * 4 + r;
                p[t * 4 + r] = (ka <= qg) ? s[t][r] : -1e30f;
            }
        float tm = p[0];
        #pragma unroll
        for (int i = 1; i < 16; ++i) tm = fmaxf(tm, p[i]);
        tm = fmaxf(tm, __shfl_xor(tm, 16));
        tm = fmaxf(tm, __shfl_xor(tm, 32));
        float mnew = fmaxf(mrow, tm);
        float corr = __expf(mrow - mnew);
        float psum = 0.f;
        #pragma unroll
        for (int i = 0; i < 16; ++i) { p[i] = __expf(p[i] - mnew); psum += p[i]; }
        psum += __shfl_xor(psum, 16);
        psum += __shfl_xor(psum, 32);
        lrow = lrow * corr + psum;
        mrow = mnew;
        o[0] *= corr; o[1] *= corr; o[2] *= corr; o[3] *= corr;

        #pragma unroll
        for (int pr = 0; pr < 2; ++pr) {
            const float* pp = p + pr * 8;
            unsigned pk0 = packbf(pp[0], pp[1]), pk1 = packbf(pp[2], pp[3]);
            unsigned pk2 = packbf(pp[4], pp[5]), pk3 = packbf(pp[6], pp[7]);
            unsigned a0 = __shfl(pk0, srcA), a1 = __shfl(pk1, srcA);
            unsigned a2 = __shfl(pk0, srcB), a3 = __shfl(pk1, srcB);
            unsigned b0 = __shfl(pk2, srcA), b1 = __shfl(pk3, srcA);
            unsigned b2 = __shfl(pk2, srcB), b3 = __shfl(pk3, srcB);
            uint4 pw = make_uint4(t1 ? b0 : a0, t1 ? b1 : a1, t1 ? b2 : a2, t1 ? b3 : a3);
            uint4 vv = *(const uint4*)(vbase + (kt0 + pr * 2) * 16 + h * 8);
            o = __builtin_amdgcn_mfma_f32_16x16x32_bf16(__builtin_bit_cast(bf16x8, vv),
                                                        __builtin_bit_cast(bf16x8, pw), o, 0, 0, 0);
        }
    }
    float inv = 1.0f / lrow;
    int bI = bh >> 3, hh = bh & 7;
    unsigned short* op = out + ((size_t)bI * Ss + qg) * Dm + hh * 16 + h * 4;
    *(uint2*)op = make_uint2(packbf(o[0] * inv, o[1] * inv),
                             packbf(o[2] * inv, o[3] * inv));
}

// ---------- generic token GEMM (R9-proven): bf16 in (opt LN); mode 0: bf16 out, 1: f32 relu ----------

__global__ __launch_bounds__(256) void gemm2(const unsigned short* __restrict__ in,
                                             const unsigned short* __restrict__ wf,
                                             const float* __restrict__ bias,
                                             const float* __restrict__ lng,
                                             const float* __restrict__ lnb,
                                             void* __restrict__ outv, int mode) {
    __shared__ unsigned short hs[80][136];
    int tid = threadIdx.x;
    int lane = tid & 63, w = tid >> 6;
    int swz = (blockIdx.x & 7) * 40 + (blockIdx.x >> 3);   // bijection on [0,320)
    size_t tok0 = (size_t)swz * 80;
    const unsigned short* ib = in + tok0 * Dm;
    if (lng) {
        for (int c = tid; c < 80 * 16; c += 256) {
            int row = c >> 4, c16 = c & 15;
            *(uint4*)&hs[row][c16 * 8] = ln_pack_bf(ib + (size_t)row * Dm + c16 * 8, lng, lnb, c16);
        }
    } else {
        for (int c = tid; c < 80 * 16; c += 256) {
            int row = c >> 4, c16 = c & 15;
            *(uint4*)&hs[row][c16 * 8] = *(const uint4*)(ib + (size_t)row * Dm + c16 * 8);
        }
    }
    __syncthreads();

    f32x4 acc[2][5];
    #pragma unroll
    for (int n = 0; n < 2; ++n)
        #pragma unroll
        for (int m = 0; m < 5; ++m) acc[n][m] = (f32x4){0.f, 0.f, 0.f, 0.f};

    int nb0 = w * 2;
    int arow = lane & 15, acol = (lane >> 4) * 8;
    #pragma unroll
    for (int kb = 0; kb < 4; ++kb) {
        bf16x8 b0 = *(const bf16x8*)(wf + ((size_t)(kb * 8 + nb0)) * 512 + lane * 8);
        bf16x8 b1 = *(const bf16x8*)(wf + ((size_t)(kb * 8 + nb0 + 1)) * 512 + lane * 8);
        #pragma unroll
        for (int m = 0; m < 5; ++m) {
            bf16x8 af = *(const bf16x8*)&hs[m * 16 + arow][kb * 32 + acol];
            acc[0][m] = __builtin_amdgcn_mfma_f32_16x16x32_bf16(af, b0, acc[0][m], 0, 0, 0);
            acc[1][m] = __builtin_amdgcn_mfma_f32_16x16x32_bf16(af, b1, acc[1][m], 0, 0, 0);
        }
    }
    int rr = (lane >> 4) * 4;
    #pragma unroll
    for (int n = 0; n < 2; ++n) {
        int f0 = (nb0 + n) * 16;
        float bvv = bias[f0 + arow];
        #pragma unroll
        for (int m = 0; m < 5; ++m)
            #pragma unroll
            for (int r = 0; r < 4; ++r) {
                float v = acc[n][m][r] + bvv;
                if (mode == 1) {
                    ((float*)outv)[(tok0 + m * 16 + rr + r) * Dm + f0 + arow] = fmaxf(v, 0.f);
                } else {
                    ((unsigned short*)outv)[(tok0 + m * 16 + rr + r) * Dm + f0 + arow] = f2bf(v);
                }
            }
    }
}

// ---------- launch ----------

extern "C" void kernel_launch(void* const* d_in, const int* in_sizes, int n_in,
                              void* d_out, int out_size, void* d_ws, size_t ws_size,
                              hipStream_t stream) {
    (void)in_sizes; (void)n_in; (void)out_size; (void)ws_size;
    const float* x       = (const float*)d_in[0];
    const float* ln_g    = (const float*)d_in[1];
    const float* ln_b    = (const float*)d_in[2];
    const float* dw_w    = (const float*)d_in[3];
    const float* dw_b    = (const float*)d_in[4];
    const float* pw_w    = (const float*)d_in[5];
    const float* pw_b    = (const float*)d_in[6];
    const float* attln_g = (const float*)d_in[7];
    const float* attln_b = (const float*)d_in[8];
    const float* wq = (const float*)d_in[9];
    const float* bq = (const float*)d_in[10];
    const float* wk = (const float*)d_in[11];
    const float* bk = (const float*)d_in[12];
    const float* wv = (const float*)d_in[13];
    const float* bv = (const float*)d_in[14];
    const float* wp = (const float*)d_in[15];
    const float* bp = (const float*)d_in[16];
    const float* ffnln_g = (const float*)d_in[17];
    const float* ffnln_b = (const float*)d_in[18];
    const float* fc_w = (const float*)d_in[19];
    const float* fc_b = (const float*)d_in[20];

    float* ws = (float*)d_ws;
    float* pe = ws;                                      // 51200 f
    float* mb = pe + 51200;                              // 512 f
    unsigned short* mwf = (unsigned short*)(mb + 512);   // 458752 u16
    unsigned short* wfb = mwf + 458752;                  // 81920 u16
    unsigned short* C1  = wfb + 81920;                   // 3276800 u16
    unsigned short* C2  = C1 + 3276800;                  // 3276800 u16
    unsigned short* Qb  = C2 + 3276800;                  // 3276800 u16
    unsigned short* Kb2 = Qb + 3276800;                  // 3276800 u16
    unsigned short* VTb = Kb2 + 3276800;                 // 3670016 u16
    unsigned short* A1b = VTb + 3670016;                 // 3276800 u16

    prep_all<<<580, 256, 0, stream>>>(wq, wk, wv, wp, fc_w, pw_w, dw_w, dw_b, pw_b,
                                      pe, wfb, mb, mwf);

    // conv stack (R7 structure)
    conv_mfma<<<Bb * 9, 512, 0, stream>>>(nullptr, x, pe, mwf,              mb,          ln_g,          ln_b,          C1);
    conv_mfma<<<Bb * 9, 512, 0, stream>>>(C1, nullptr, nullptr, mwf + 114688,     mb + Dm,     ln_g + Dm,     ln_b + Dm,     C2);
    conv_mfma<<<Bb * 9, 512, 0, stream>>>(C2, nullptr, nullptr, mwf + 2 * 114688, mb + 2 * Dm, ln_g + 2 * Dm, ln_b + 2 * Dm, C1);
    conv_mfma<<<Bb * 9, 512, 0, stream>>>(C1, nullptr, nullptr, mwf + 3 * 114688, mb + 3 * Dm, ln_g + 3 * Dm, ln_b + 3 * Dm, C2);

    // fused QKV
    qkv_mfma<<<dim3(320, 2), 256, 0, stream>>>(C2, attln_g, attln_b, wfb, bq, bk, bv, Qb, Kb2, VTb);

    // attention (R9-proven shuffle path)
    attn_mfma<<<dim3(512, 5), 320, 0, stream>>>(Qb, Kb2, VTb, A1b);

    // proj (bf16 out) then ffn (LN inline, relu f32 out) — R9-proven split
    gemm2<<<320, 256, 0, stream>>>(A1b, wfb + 3 * 16384, bp, nullptr, nullptr, C1, 0);
    gemm2<<<320, 256, 0, stream>>>(C1, wfb + 4 * 16384, fc_b, ffnln_g, ffnln_b, d_out, 1);
}

// Round 14
// 117.514 us; speedup vs baseline: 1.0794x; 1.0178x over previous
//
#include <hip/hip_runtime.h>
#include <hip/hip_bf16.h>
#include <math.h>

#define Dm 128
#define Lc 4
#define Kc 7
#define Hh 8
#define Bb 64
#define Ss 400
#define SsP 448
#define TOK (Bb*Ss)

typedef __attribute__((ext_vector_type(8))) short bf16x8;
typedef __attribute__((ext_vector_type(4))) float f32x4;

__device__ __forceinline__ float bf2f(unsigned int u) {
    union { unsigned int i; float f; } x; x.i = u << 16; return x.f;
}
__device__ __forceinline__ unsigned short f2bf(float f) {
    __hip_bfloat16 h = __float2bfloat16(f);
    return __builtin_bit_cast(unsigned short, h);
}
__device__ __forceinline__ unsigned int packbf(float a, float b) {
    return (unsigned int)f2bf(a) | ((unsigned int)f2bf(b) << 16);
}

// ---------- fused prep: pe (200) + repack_w (320) + merge_bias (4) + merge_conv (56) ----------

__global__ __launch_bounds__(256) void prep_all(const float* __restrict__ wq, const float* __restrict__ wk,
                                                const float* __restrict__ wv, const float* __restrict__ wp,
                                                const float* __restrict__ fc,
                                                const float* __restrict__ pw_w, const float* __restrict__ dw_w,
                                                const float* __restrict__ dw_b, const float* __restrict__ pw_b,
                                                float* __restrict__ pe, unsigned short* __restrict__ wf,
                                                float* __restrict__ mb, unsigned short* __restrict__ mwf) {
    __shared__ unsigned short hiS[64][136];
    __shared__ unsigned short loS[64][136];
    int blk = blockIdx.x;
    int tid = threadIdx.x;
    if (blk < 200) {
        int s = blk * 2 + (tid >> 7);
        int c = tid & 127;
        int j = (c < 64) ? c : (c - 64);
        float freq = expf(-(2.0f * j / 128.0f) * 9.210340371976184f);
        float a = (float)s * freq;
        pe[s * Dm + c] = (c < 64) ? sinf(a) : cosf(a);
        return;
    }
    if (blk < 520) {
        int idx = (blk - 200) * 256 + tid;
        int m = idx >> 14;
        int r = idx & 16383;
        int fragi = r >> 9, lr = (r >> 3) & 63, j = r & 7;
        int kb = fragi >> 3, nb = fragi & 7;
        int o = nb * 16 + (lr & 15);
        int d = kb * 32 + (lr >> 4) * 8 + j;
        const float* src = (m == 0) ? wq : (m == 1) ? wk : (m == 2) ? wv : (m == 3) ? wp : fc;
        wf[idx] = f2bf(src[o * Dm + d]);
        return;
    }
    if (blk < 524) {
        int l = blk - 520;
        int f = tid;
        if (f < Dm) {
            const float* pwl = pw_w + ((size_t)l * Dm + f) * Dm;
            const float* db  = dw_b + l * Dm;
            float acc = pw_b[l * Dm + f];
            #pragma unroll 8
            for (int c4 = 0; c4 < 32; ++c4) {
                float4 p = *(const float4*)(pwl + c4 * 4);
                float4 d = *(const float4*)(db + c4 * 4);
                acc += p.x * d.x + p.y * d.y + p.z * d.z + p.w * d.w;
            }
            mb[l * Dm + f] = acc;
        }
        return;
    }
    int mblk = blk - 524;
    int ih = mblk & 1;
    int k  = (mblk >> 1) % 7;
    int l  = mblk / 14;
    int lane = tid & 63, w = tid >> 6;

    const float* dwl = dw_w + (size_t)l * (Dm * Dm * Kc) + k;
    for (int it = 0; it < 32; ++it) {
        int idx = it * 256 + tid;
        int c = idx >> 6, il = idx & 63;
        int i = ih * 64 + il;
        float x = dwl[(size_t)(c * Dm + i) * Kc];
        unsigned short hi = f2bf(x);
        float lo = x - bf2f(hi);
        hiS[il][c] = hi;
        loS[il][c] = f2bf(lo);
    }
    __syncthreads();

    const float* pwl = pw_w + (size_t)l * Dm * Dm;
    int arow = lane & 15, ac = (lane >> 4) * 8;
    f32x4 acc[2][4];
    #pragma unroll
    for (int n = 0; n < 2; ++n)
        #pragma unroll
        for (int m = 0; m < 4; ++m) acc[n][m] = (f32x4){0.f, 0.f, 0.f, 0.f};

    #pragma unroll
    for (int kb = 0; kb < 4; ++kb) {
        int c0 = kb * 32 + ac;
        bf16x8 Bhi[2], Blo[2];
        #pragma unroll
        for (int n = 0; n < 2; ++n) {
            int f = (w * 2 + n) * 16 + arow;
            const float* rp = pwl + (size_t)f * Dm + c0;
            float4 a = *(const float4*)rp;
            float4 b = *(const float4*)(rp + 4);
            float v[8] = {a.x, a.y, a.z, a.w, b.x, b.y, b.z, b.w};
            unsigned short hh[8], ll[8];
            #pragma unroll
            for (int j = 0; j < 8; ++j) {
                hh[j] = f2bf(v[j]);
                ll[j] = f2bf(v[j] - bf2f(hh[j]));
            }
            uint4 uh = make_uint4((unsigned)hh[0] | ((unsigned)hh[1] << 16),
                                  (unsigned)hh[2] | ((unsigned)hh[3] << 16),
                                  (unsigned)hh[4] | ((unsigned)hh[5] << 16),
                                  (unsigned)hh[6] | ((unsigned)hh[7] << 16));
            uint4 ul = make_uint4((unsigned)ll[0] | ((unsigned)ll[1] << 16),
                                  (unsigned)ll[2] | ((unsigned)ll[3] << 16),
                                  (unsigned)ll[4] | ((unsigned)ll[5] << 16),
                                  (unsigned)ll[6] | ((unsigned)ll[7] << 16));
            Bhi[n] = __builtin_bit_cast(bf16x8, uh);
            Blo[n] = __builtin_bit_cast(bf16x8, ul);
        }
        #pragma unroll
        for (int m = 0; m < 4; ++m) {
            bf16x8 ahi = *(const bf16x8*)&hiS[m * 16 + arow][c0];
            bf16x8 alo = *(const bf16x8*)&loS[m * 16 + arow][c0];
            #pragma unroll
            for (int n = 0; n < 2; ++n) {
                acc[n][m] = __builtin_amdgcn_mfma_f32_16x16x32_bf16(ahi, Bhi[n], acc[n][m], 0, 0, 0);
                acc[n][m] = __builtin_amdgcn_mfma_f32_16x16x32_bf16(ahi, Blo[n], acc[n][m], 0, 0, 0);
                acc[n][m] = __builtin_amdgcn_mfma_f32_16x16x32_bf16(alo, Bhi[n], acc[n][m], 0, 0, 0);
            }
        }
    }
    #pragma unroll
    for (int n = 0; n < 2; ++n) {
        int nb = w * 2 + n;
        #pragma unroll
        for (int m = 0; m < 4; ++m) {
            int i0 = ih * 64 + m * 16 + (lane >> 4) * 4;
            int ib = i0 >> 5, i32 = i0 & 31;
            int lanep = ((i32 >> 3) << 4) | arow;
            int jb = i32 & 7;
            size_t frag = ((size_t)(l * 28 + (k * 4 + ib)) * 8 + nb);
            *(uint2*)(mwf + frag * 512 + lanep * 8 + jb) =
                make_uint2(packbf(acc[n][m][0], acc[n][m][1]),
                           packbf(acc[n][m][2], acc[n][m][3]));
        }
    }
}

// ---------- LN helpers ----------

__device__ __forceinline__ uint4 ln_core(float v[8],
                                         const float* __restrict__ g,
                                         const float* __restrict__ b, int c16) {
    float sum = 0.f, sq = 0.f;
    #pragma unroll
    for (int j = 0; j < 8; ++j) { sum += v[j]; sq += v[j] * v[j]; }
    #pragma unroll
    for (int off = 8; off; off >>= 1) {
        sum += __shfl_xor(sum, off);
        sq  += __shfl_xor(sq, off);
    }
    float mu = sum * (1.0f / 128.0f);
    float var = sq * (1.0f / 128.0f) - mu * mu;
    float rs = rsqrtf(var + 1e-5f);
    float4 g0 = *(const float4*)(g + c16 * 8);
    float4 g1 = *(const float4*)(g + c16 * 8 + 4);
    float4 b0 = *(const float4*)(b + c16 * 8);
    float4 b1 = *(const float4*)(b + c16 * 8 + 4);
    uint4 o;
    o.x = packbf((v[0] - mu) * rs * g0.x + b0.x, (v[1] - mu) * rs * g0.y + b0.y);
    o.y = packbf((v[2] - mu) * rs * g0.z + b0.z, (v[3] - mu) * rs * g0.w + b0.w);
    o.z = packbf((v[4] - mu) * rs * g1.x + b1.x, (v[5] - mu) * rs * g1.y + b1.y);
    o.w = packbf((v[6] - mu) * rs * g1.z + b1.z, (v[7] - mu) * rs * g1.w + b1.w);
    return o;
}

__device__ __forceinline__ uint4 ln_pack_bf(const unsigned short* __restrict__ rp,
                                            const float* __restrict__ g,
                                            const float* __restrict__ b, int c16) {
    uint4 u = *(const uint4*)rp;
    float v[8] = { bf2f(u.x & 0xffffu), bf2f(u.x >> 16), bf2f(u.y & 0xffffu), bf2f(u.y >> 16),
                   bf2f(u.z & 0xffffu), bf2f(u.z >> 16), bf2f(u.w & 0xffffu), bf2f(u.w >> 16) };
    return ln_core(v, g, b, c16);
}

// ---------- conv (R7-proven): M=48/block, 8 waves x (1nb x 3m), bf16 act; XCD swizzle ----------

__global__ __launch_bounds__(512) void conv_mfma(const unsigned short* __restrict__ in16,
                                                 const float* __restrict__ in32,
                                                 const float* __restrict__ pe,
                                                 const unsigned short* __restrict__ mwf,
                                                 const float* __restrict__ mb,
                                                 const float* __restrict__ lng,
                                                 const float* __restrict__ lnb,
                                                 unsigned short* __restrict__ out) {
    __shared__ unsigned short hs[54][136];
    int tid = threadIdx.x;
    int lane = tid & 63, w = tid >> 6;
    int swz = (blockIdx.x & 7) * 72 + (blockIdx.x >> 3);   // bijection on [0,576)
    int bI = swz / 9;
    int st = swz % 9;
    int s0 = st * 48;
    for (int c = tid; c < 54 * 16; c += 512) {
        int row = c >> 4, c16 = c & 15;
        int gs = s0 - 3 + row;
        uint4 o = make_uint4(0u, 0u, 0u, 0u);
        if (gs >= 0 && gs < Ss) {
            if (in32) {
                const float* rp = in32 + ((size_t)bI * Ss + gs) * Dm + c16 * 8;
                const float* pp = pe + (size_t)gs * Dm + c16 * 8;
                float v[8];
                #pragma unroll
                for (int j = 0; j < 8; ++j) v[j] = rp[j] + pp[j];
                o = ln_core(v, lng, lnb, c16);
            } else {
                o = ln_pack_bf(in16 + ((size_t)bI * Ss + gs) * Dm + c16 * 8, lng, lnb, c16);
            }
        }
        *(uint4*)&hs[row][c16 * 8] = o;
    }
    __syncthreads();

    f32x4 acc[3];
    #pragma unroll
    for (int m = 0; m < 3; ++m) acc[m] = (f32x4){0.f, 0.f, 0.f, 0.f};

    int nb = w;
    int arow = lane & 15, acol = (lane >> 4) * 8;
    #pragma unroll 4
    for (int kb = 0; kb < 28; ++kb) {
        int k = kb >> 2, i0 = (kb & 3) * 32;
        bf16x8 bfr = *(const bf16x8*)(mwf + ((size_t)(kb * 8 + nb)) * 512 + lane * 8);
        #pragma unroll
        for (int m = 0; m < 3; ++m) {
            bf16x8 af = *(const bf16x8*)&hs[m * 16 + arow + k][i0 + acol];
            acc[m] = __builtin_amdgcn_mfma_f32_16x16x32_bf16(af, bfr, acc[m], 0, 0, 0);
        }
    }
    int rr = (lane >> 4) * 4;
    int f0 = nb * 16;
    float bias = mb[f0 + arow];
    #pragma unroll
    for (int m = 0; m < 3; ++m)
        #pragma unroll
        for (int r = 0; r < 4; ++r) {
            int s = s0 + m * 16 + rr + r;
            if (s < Ss)
                out[((size_t)bI * Ss + s) * Dm + f0 + arow] = f2bf(acc[m][r] + bias);
        }
}

// ---------- fused QKV (R7-proven): grid (320, 2). y=0: Q+K; y=1: V^T ----------

__global__ __launch_bounds__(256) void qkv_mfma(const unsigned short* __restrict__ in,
                                                const float* __restrict__ lng,
                                                const float* __restrict__ lnb,
                                                const unsigned short* __restrict__ wfb,
                                                const float* __restrict__ bq,
                                                const float* __restrict__ bk,
                                                const float* __restrict__ bv,
                                                unsigned short* __restrict__ Qo,
                                                unsigned short* __restrict__ Ko,
                                                unsigned short* __restrict__ Vo) {
    __shared__ unsigned short hs[80][136];
    int tid = threadIdx.x;
    int lane = tid & 63, w = tid >> 6;
    int y = blockIdx.y;
    int swz = (blockIdx.x & 7) * 40 + (blockIdx.x >> 3);   // bijection on [0,320)
    int bI = swz / 5;
    int sb = (swz % 5) * 80;
    const unsigned short* ib = in + ((size_t)bI * Ss + sb) * Dm;
    for (int c = tid; c < 80 * 16; c += 256) {
        int row = c >> 4, c16 = c & 15;
        *(uint4*)&hs[row][c16 * 8] = ln_pack_bf(ib + (size_t)row * Dm + c16 * 8, lng, lnb, c16);
    }
    __syncthreads();

    int nb0 = w * 2;
    int arow = lane & 15, acol = (lane >> 4) * 8;
    int nmat = (y == 0) ? 2 : 1;
    for (int mi = 0; mi < nmat; ++mi) {
        int mat = (y == 0) ? mi : 2;
        const unsigned short* wf = wfb + (size_t)mat * 16384;
        f32x4 acc[2][5];
        #pragma unroll
        for (int n = 0; n < 2; ++n)
            #pragma unroll
            for (int m = 0; m < 5; ++m) acc[n][m] = (f32x4){0.f, 0.f, 0.f, 0.f};
        #pragma unroll
        for (int kb = 0; kb < 4; ++kb) {
            bf16x8 b0 = *(const bf16x8*)(wf + ((size_t)(kb * 8 + nb0)) * 512 + lane * 8);
            bf16x8 b1 = *(const bf16x8*)(wf + ((size_t)(kb * 8 + nb0 + 1)) * 512 + lane * 8);
            #pragma unroll
            for (int m = 0; m < 5; ++m) {
                bf16x8 af = *(const bf16x8*)&hs[m * 16 + arow][kb * 32 + acol];
                acc[0][m] = __builtin_amdgcn_mfma_f32_16x16x32_bf16(af, b0, acc[0][m], 0, 0, 0);
                acc[1][m] = __builtin_amdgcn_mfma_f32_16x16x32_bf16(af, b1, acc[1][m], 0, 0, 0);
            }
        }
        int rr = (lane >> 4) * 4;
        const float* bias = (mat == 0) ? bq : (mat == 1) ? bk : bv;
        float sc = (mat == 0) ? 0.25f : 1.0f;
        #pragma unroll
        for (int n = 0; n < 2; ++n) {
            int hI = nb0 + n;
            float bvv = bias[hI * 16 + arow];
            if (mat < 2) {
                unsigned short* qo = (mat == 0) ? Qo : Ko;
                #pragma unroll
                for (int m = 0; m < 5; ++m)
                    #pragma unroll
                    for (int r = 0; r < 4; ++r) {
                        int s = sb + m * 16 + rr + r;
                        qo[(((size_t)(bI * Hh + hI)) * Ss + s) * 16 + arow] = f2bf((acc[n][m][r] + bvv) * sc);
                    }
            } else {
                unsigned short* base = Vo + ((size_t)(bI * Hh + hI) * 16 + arow) * SsP + sb;
                #pragma unroll
                for (int m = 0; m < 5; ++m) {
                    unsigned lo = packbf(acc[n][m][0] + bvv, acc[n][m][1] + bvv);
                    unsigned hi = packbf(acc[n][m][2] + bvv, acc[n][m][3] + bvv);
                    *(uint2*)(base + m * 16 + rr) = make_uint2(lo, hi);
                }
            }
        }
    }
}

// ---------- flash attention: online-max (R13 numerics) + LDS P-path + unmasked fast path ----------
// Wave-private pb write->read fenced by lgkmcnt(0) + sched_barrier(0) (guide rule #18).

__global__ __launch_bounds__(320) void attn_mfma(const unsigned short* __restrict__ Q,
                                                 const unsigned short* __restrict__ Kb,
                                                 const unsigned short* __restrict__ VT,
                                                 unsigned short* __restrict__ out) {
    __shared__ unsigned short pb[5][16][68];   // per-wave P tile; 136B row stride (8B-aligned)
    int wid = threadIdx.x >> 6, lane = threadIdx.x & 63;
    int bh = (blockIdx.x & 7) * 64 + (blockIdx.x >> 3);   // bijection on [0,512)
    int qt = blockIdx.y * 5 + wid;           // 0..24
    int q15 = lane & 15, h = lane >> 4;
    int qg = qt * 16 + q15;

    uint4 qv = make_uint4(0u, 0u, 0u, 0u);
    if (h < 2) qv = *(const uint4*)(Q + ((size_t)bh * Ss + qg) * 16 + h * 8);
    bf16x8 qf = __builtin_bit_cast(bf16x8, qv);

    f32x4 o = (f32x4){0.f, 0.f, 0.f, 0.f};
    float mrow = -1e30f, lrow = 0.f;
    const unsigned short* kbase = Kb + (size_t)bh * Ss * 16;
    const unsigned short* vbase = VT + ((size_t)bh * 16 + q15) * SsP;
    unsigned short* prow = &pb[wid][q15][0];
    f32x4 z = (f32x4){0.f, 0.f, 0.f, 0.f};

    for (int kt0 = 0; kt0 <= qt; kt0 += 4) {     // 64 k per chunk
        uint4 kv[4];
        #pragma unroll
        for (int t = 0; t < 4; ++t) {
            kv[t] = make_uint4(0u, 0u, 0u, 0u);
            if (h < 2 && kt0 + t <= qt)
                kv[t] = *(const uint4*)(kbase + (size_t)((kt0 + t) * 16 + q15) * 16 + h * 8);
        }
        f32x4 s[4];
        #pragma unroll
        for (int t = 0; t < 4; ++t)
            s[t] = __builtin_amdgcn_mfma_f32_16x16x32_bf16(__builtin_bit_cast(bf16x8, kv[t]), qf, z, 0, 0, 0);

        float p[16];
        if (kt0 + 4 <= qt) {                     // fully-unmasked chunk (wave-uniform, same values)
            #pragma unroll
            for (int t = 0; t < 4; ++t)
                #pragma unroll
                for (int r = 0; r < 4; ++r) p[t * 4 + r] = s[t][r];
        } else {
            #pragma unroll
            for (int t = 0; t < 4; ++t)
                #pragma unroll
                for (int r = 0; r < 4; ++r) {
                    int ka = (kt0 + t) * 16 + h * 4 + r;
                    p[t * 4 + r] = (ka <= qg) ? s[t][r] : -1e30f;
                }
        }
        float tm = p[0];
        #pragma unroll
        for (int i = 1; i < 16; ++i) tm = fmaxf(tm, p[i]);
        tm = fmaxf(tm, __shfl_xor(tm, 16));
        tm = fmaxf(tm, __shfl_xor(tm, 32));
        float mnew = fmaxf(mrow, tm);
        float corr = __expf(mrow - mnew);
        float psum = 0.f;
        #pragma unroll
        for (int i = 0; i < 16; ++i) { p[i] = __expf(p[i] - mnew); psum += p[i]; }
        psum += __shfl_xor(psum, 16);
        psum += __shfl_xor(psum, 32);
        lrow = lrow * corr + psum;
        mrow = mnew;
        o[0] *= corr; o[1] *= corr; o[2] *= corr; o[3] *= corr;

        // P -> LDS in PV B-frag order: pb[q][k'], k' = 16t + 4h + r (wave-private)
        #pragma unroll
        for (int t = 0; t < 4; ++t)
            *(uint2*)(prow + t * 16 + h * 4) =
                make_uint2(packbf(p[4 * t], p[4 * t + 1]), packbf(p[4 * t + 2], p[4 * t + 3]));
        __asm__ volatile("s_waitcnt lgkmcnt(0)" ::: "memory");
        __builtin_amdgcn_sched_barrier(0);       // rule #18: stop MFMA hoisting past the wait

        #pragma unroll
        for (int pr = 0; pr < 2; ++pr) {
            bf16x8 pwf = *(const bf16x8*)(prow + pr * 32 + h * 8);
            uint4 vv = *(const uint4*)(vbase + (kt0 + pr * 2) * 16 + h * 8);
            o = __builtin_amdgcn_mfma_f32_16x16x32_bf16(__builtin_bit_cast(bf16x8, vv),
                                                        pwf, o, 0, 0, 0);
        }
    }
    float inv = 1.0f / lrow;
    int bI = bh >> 3, hh = bh & 7;
    unsigned short* op = out + ((size_t)bI * Ss + qg) * Dm + hh * 16 + h * 4;
    *(uint2*)op = make_uint2(packbf(o[0] * inv, o[1] * inv),
                             packbf(o[2] * inv, o[3] * inv));
}

// ---------- generic token GEMM (R9-proven): bf16 in (opt LN); mode 0: bf16 out, 1: f32 relu ----------

__global__ __launch_bounds__(256) void gemm2(const unsigned short* __restrict__ in,
                                             const unsigned short* __restrict__ wf,
                                             const float* __restrict__ bias,
                                             const float* __restrict__ lng,
                                             const float* __restrict__ lnb,
                                             void* __restrict__ outv, int mode) {
    __shared__ unsigned short hs[80][136];
    int tid = threadIdx.x;
    int lane = tid & 63, w = tid >> 6;
    int swz = (blockIdx.x & 7) * 40 + (blockIdx.x >> 3);   // bijection on [0,320)
    size_t tok0 = (size_t)swz * 80;
    const unsigned short* ib = in + tok0 * Dm;
    if (lng) {
        for (int c = tid; c < 80 * 16; c += 256) {
            int row = c >> 4, c16 = c & 15;
            *(uint4*)&hs[row][c16 * 8] = ln_pack_bf(ib + (size_t)row * Dm + c16 * 8, lng, lnb, c16);
        }
    } else {
        for (int c = tid; c < 80 * 16; c += 256) {
            int row = c >> 4, c16 = c & 15;
            *(uint4*)&hs[row][c16 * 8] = *(const uint4*)(ib + (size_t)row * Dm + c16 * 8);
        }
    }
    __syncthreads();

    f32x4 acc[2][5];
    #pragma unroll
    for (int n = 0; n < 2; ++n)
        #pragma unroll
        for (int m = 0; m < 5; ++m) acc[n][m] = (f32x4){0.f, 0.f, 0.f, 0.f};

    int nb0 = w * 2;
    int arow = lane & 15, acol = (lane >> 4) * 8;
    #pragma unroll
    for (int kb = 0; kb < 4; ++kb) {
        bf16x8 b0 = *(const bf16x8*)(wf + ((size_t)(kb * 8 + nb0)) * 512 + lane * 8);
        bf16x8 b1 = *(const bf16x8*)(wf + ((size_t)(kb * 8 + nb0 + 1)) * 512 + lane * 8);
        #pragma unroll
        for (int m = 0; m < 5; ++m) {
            bf16x8 af = *(const bf16x8*)&hs[m * 16 + arow][kb * 32 + acol];
            acc[0][m] = __builtin_amdgcn_mfma_f32_16x16x32_bf16(af, b0, acc[0][m], 0, 0, 0);
            acc[1][m] = __builtin_amdgcn_mfma_f32_16x16x32_bf16(af, b1, acc[1][m], 0, 0, 0);
        }
    }
    int rr = (lane >> 4) * 4;
    #pragma unroll
    for (int n = 0; n < 2; ++n) {
        int f0 = (nb0 + n) * 16;
        float bvv = bias[f0 + arow];
        #pragma unroll
        for (int m = 0; m < 5; ++m)
            #pragma unroll
            for (int r = 0; r < 4; ++r) {
                float v = acc[n][m][r] + bvv;
                if (mode == 1) {
                    ((float*)outv)[(tok0 + m * 16 + rr + r) * Dm + f0 + arow] = fmaxf(v, 0.f);
                } else {
                    ((unsigned short*)outv)[(tok0 + m * 16 + rr + r) * Dm + f0 + arow] = f2bf(v);
                }
            }
    }
}

// ---------- launch ----------

extern "C" void kernel_launch(void* const* d_in, const int* in_sizes, int n_in,
                              void* d_out, int out_size, void* d_ws, size_t ws_size,
                              hipStream_t stream) {
    (void)in_sizes; (void)n_in; (void)out_size; (void)ws_size;
    const float* x       = (const float*)d_in[0];
    const float* ln_g    = (const float*)d_in[1];
    const float* ln_b    = (const float*)d_in[2];
    const float* dw_w    = (const float*)d_in[3];
    const float* dw_b    = (const float*)d_in[4];
    const float* pw_w    = (const float*)d_in[5];
    const float* pw_b    = (const float*)d_in[6];
    const float* attln_g = (const float*)d_in[7];
    const float* attln_b = (const float*)d_in[8];
    const float* wq = (const float*)d_in[9];
    const float* bq = (const float*)d_in[10];
    const float* wk = (const float*)d_in[11];
    const float* bk = (const float*)d_in[12];
    const float* wv = (const float*)d_in[13];
    const float* bv = (const float*)d_in[14];
    const float* wp = (const float*)d_in[15];
    const float* bp = (const float*)d_in[16];
    const float* ffnln_g = (const float*)d_in[17];
    const float* ffnln_b = (const float*)d_in[18];
    const float* fc_w = (const float*)d_in[19];
    const float* fc_b = (const float*)d_in[20];

    float* ws = (float*)d_ws;
    float* pe = ws;                                      // 51200 f
    float* mb = pe + 51200;                              // 512 f
    unsigned short* mwf = (unsigned short*)(mb + 512);   // 458752 u16
    unsigned short* wfb = mwf + 458752;                  // 81920 u16
    unsigned short* C1  = wfb + 81920;                   // 3276800 u16
    unsigned short* C2  = C1 + 3276800;                  // 3276800 u16
    unsigned short* Qb  = C2 + 3276800;                  // 3276800 u16
    unsigned short* Kb2 = Qb + 3276800;                  // 3276800 u16
    unsigned short* VTb = Kb2 + 3276800;                 // 3670016 u16
    unsigned short* A1b = VTb + 3670016;                 // 3276800 u16

    prep_all<<<580, 256, 0, stream>>>(wq, wk, wv, wp, fc_w, pw_w, dw_w, dw_b, pw_b,
                                      pe, wfb, mb, mwf);

    // conv stack (R7 structure, XCD swizzle)
    conv_mfma<<<Bb * 9, 512, 0, stream>>>(nullptr, x, pe, mwf,              mb,          ln_g,          ln_b,          C1);
    conv_mfma<<<Bb * 9, 512, 0, stream>>>(C1, nullptr, nullptr, mwf + 114688,     mb + Dm,     ln_g + Dm,     ln_b + Dm,     C2);
    conv_mfma<<<Bb * 9, 512, 0, stream>>>(C2, nullptr, nullptr, mwf + 2 * 114688, mb + 2 * Dm, ln_g + 2 * Dm, ln_b + 2 * Dm, C1);
    conv_mfma<<<Bb * 9, 512, 0, stream>>>(C1, nullptr, nullptr, mwf + 3 * 114688, mb + 3 * Dm, ln_g + 3 * Dm, ln_b + 3 * Dm, C2);

    // fused QKV
    qkv_mfma<<<dim3(320, 2), 256, 0, stream>>>(C2, attln_g, attln_b, wfb, bq, bk, bv, Qb, Kb2, VTb);

    // attention (LDS P-path + fast path, fenced per rule #18)
    attn_mfma<<<dim3(512, 5), 320, 0, stream>>>(Qb, Kb2, VTb, A1b);

    // proj (bf16 out) then ffn (LN inline, relu f32 out)
    gemm2<<<320, 256, 0, stream>>>(A1b, wfb + 3 * 16384, bp, nullptr, nullptr, C1, 0);
    gemm2<<<320, 256, 0, stream>>>(C1, wfb + 4 * 16384, fc_b, ffnln_g, ffnln_b, d_out, 1);
}